// Round 12
// baseline (177.328 us; speedup 1.0000x reference)
//
#include <hip/hip_runtime.h>

#define BATCH 4
#define SEQ   2048
#define EMB   512
#define HEADS 8
#define HD    64

typedef _Float16 half2_t __attribute__((ext_vector_type(2)));
typedef _Float16 half4_t __attribute__((ext_vector_type(4)));
typedef _Float16 half8_t __attribute__((ext_vector_type(8)));
typedef float    f32x4   __attribute__((ext_vector_type(4)));

#if __has_builtin(__builtin_amdgcn_exp2f)
#define EXP2F(x) __builtin_amdgcn_exp2f(x)
#else
#define EXP2F(x) exp2f(x)
#endif
#define LOG2E 1.44269504088896f

#define PKRTZ(a, b) __builtin_bit_cast(half2_t, __builtin_amdgcn_cvt_pkrtz((a), (b)))

// ---------------------------------------------------------------- mod factor
__global__ void mod_kernel(const float* __restrict__ emo, float* __restrict__ modv){
    int lane = threadIdx.x;                 // 64 threads, 1 wave
    for (int b = 0; b < BATCH; ++b){
        float v = emo[b*64 + lane];
        #pragma unroll
        for (int off = 32; off >= 1; off >>= 1) v += __shfl_xor(v, off, 64);
        if (lane == 0){
            float mean = v * (1.0f/64.0f);
            float sig  = 1.0f/(1.0f + __expf(-mean));
            modv[b] = 0.5f + 0.5f*sig;
        }
    }
}

__device__ inline half8_t cvt8(const float* p){
    float4 v0 = *(const float4*)p;
    float4 v1 = *(const float4*)(p + 4);
    half8_t r;
    r[0]=(_Float16)v0.x; r[1]=(_Float16)v0.y; r[2]=(_Float16)v0.z; r[3]=(_Float16)v0.w;
    r[4]=(_Float16)v1.x; r[5]=(_Float16)v1.y; r[6]=(_Float16)v1.z; r[7]=(_Float16)v1.w;
    return r;
}

__device__ inline half8_t cvt8v(float4 v0, float4 v1){
    half8_t r;
    r[0]=(_Float16)v0.x; r[1]=(_Float16)v0.y; r[2]=(_Float16)v0.z; r[3]=(_Float16)v0.w;
    r[4]=(_Float16)v1.x; r[5]=(_Float16)v1.y; r[6]=(_Float16)v1.z; r[7]=(_Float16)v1.w;
    return r;
}

// --------------------------------------- QKV projections, one launch (z=0,1,2)
// Double-buffered XOR-swizzled LDS (2 x 24 KB): next k-step's global loads
// issue into registers BEFORE current-buffer compute; cvt+ds_write after.
// One barrier per step. Swizzle/read mapping identical to R11 (verified).
// Global fragment-major outputs unchanged (R10-verified).
__global__ __launch_bounds__(256) void qkv_kernel(
    const float* __restrict__ X0, const float* __restrict__ X1, const float* __restrict__ X2,
    const float* __restrict__ W0, const float* __restrict__ W1, const float* __restrict__ W2,
    const float* __restrict__ b0, const float* __restrict__ b1, const float* __restrict__ b2,
    _Float16* __restrict__ o0, _Float16* __restrict__ o1, _Float16* __restrict__ o2)
{
    const int z = blockIdx.z;
    const float* X    = (z==0) ? X0 : (z==1) ? X1 : X2;
    const float* W    = (z==0) ? W0 : (z==1) ? W1 : W2;
    const float* bias = (z==0) ? b0 : (z==1) ? b1 : b2;
    _Float16*  out    = (z==0) ? o0 : (z==1) ? o1 : o2;

    __shared__ _Float16 lA[2][128*64];    // 2 x 16 KB row-major, swizzled chunks
    __shared__ _Float16 lB[2][64*64];     // 2 x  8 KB

    const int tid  = threadIdx.x;
    const int wid  = tid >> 6;
    const int lane = tid & 63;
    const int l16  = lane & 15;
    const int g    = lane >> 4;
    const int l7   = l16 & 7;
    const int mb = blockIdx.x;
    const int nb = blockIdx.y;
    const int wm = (wid >> 1)*64;
    const int wn = (wid & 1)*32;
    const int tR = tid >> 3;
    const int c8 = tid & 7;

    // ---- prologue: stage ks=0 into buffer 0
    #pragma unroll
    for (int p = 0; p < 4; ++p){
        const int R = p*32 + tR;
        half8_t h = cvt8(X + (size_t)(mb*128 + R)*EMB + c8*8);
        *(half8_t*)(&lA[0][R*64 + ((c8 ^ (R & 7))*8)]) = h;
    }
    #pragma unroll
    for (int p = 0; p < 2; ++p){
        const int R = p*32 + tR;
        half8_t h = cvt8(W + (size_t)(nb*64 + R)*EMB + c8*8);
        *(half8_t*)(&lB[0][R*64 + ((c8 ^ (R & 7))*8)]) = h;
    }
    __syncthreads();

    f32x4 acc[4][2] = {};
    int cur = 0;
    for (int ks = 0; ks < 8; ++ks){
        // ---- issue next step's global loads early (hidden under compute)
        float4 xa0[4], xa1[4], wb0[2], wb1[2];
        if (ks < 7){
            #pragma unroll
            for (int p = 0; p < 4; ++p){
                const float* px = X + (size_t)(mb*128 + p*32 + tR)*EMB + (ks+1)*64 + c8*8;
                xa0[p] = *(const float4*)px;
                xa1[p] = *(const float4*)(px + 4);
            }
            #pragma unroll
            for (int p = 0; p < 2; ++p){
                const float* pw = W + (size_t)(nb*64 + p*32 + tR)*EMB + (ks+1)*64 + c8*8;
                wb0[p] = *(const float4*)pw;
                wb1[p] = *(const float4*)(pw + 4);
            }
        }
        // ---- compute from buf[cur]
        #pragma unroll
        for (int u = 0; u < 2; ++u){
            half8_t af[4], bf[2];
            #pragma unroll
            for (int i = 0; i < 4; ++i){
                const int rA = wm + i*16 + l16;
                af[i] = *(half8_t*)(&lA[cur][rA*64 + (((u*4 + g) ^ l7)*8)]);
            }
            #pragma unroll
            for (int j = 0; j < 2; ++j){
                const int rB = wn + j*16 + l16;
                bf[j] = *(half8_t*)(&lB[cur][rB*64 + (((u*4 + g) ^ l7)*8)]);
            }
            #pragma unroll
            for (int i = 0; i < 4; ++i)
                #pragma unroll
                for (int j = 0; j < 2; ++j)
                    acc[i][j] = __builtin_amdgcn_mfma_f32_16x16x32_f16(af[i], bf[j], acc[i][j], 0, 0, 0);
        }
        // ---- convert + write next step into the free buffer
        if (ks < 7){
            #pragma unroll
            for (int p = 0; p < 4; ++p){
                const int R = p*32 + tR;
                *(half8_t*)(&lA[cur^1][R*64 + ((c8 ^ (R & 7))*8)]) = cvt8v(xa0[p], xa1[p]);
            }
            #pragma unroll
            for (int p = 0; p < 2; ++p){
                const int R = p*32 + tR;
                *(half8_t*)(&lB[cur^1][R*64 + ((c8 ^ (R & 7))*8)]) = cvt8v(wb0[p], wb1[p]);
            }
        }
        __syncthreads();
        cur ^= 1;
    }
    // ---- store (fragment-major out, mapping identical to R10/R11)
    #pragma unroll
    for (int j = 0; j < 2; ++j){
        const int nn  = nb*64 + wn + j*16 + l16;
        const float bn = bias[nn];
        const int h = nn >> 6, d = nn & 63;
        #pragma unroll
        for (int i = 0; i < 4; ++i){
            #pragma unroll
            for (int r = 0; r < 4; ++r){
                const int m  = mb*128 + wm + i*16 + 4*g + r;
                const int bb2 = m >> 11, s = m & 2047;
                const int bh  = bb2*8 + h;
                const float v = acc[i][j][r] + bn;
                size_t idx;
                if (z == 2)
                    idx = ((size_t)(bh*128 + (s>>4))*2 + (d>>5))*512
                        + (size_t)((((s>>2)&3)*16 + (d&15))*8 + ((d>>4)&1)*4 + (s&3));
                else
                    idx = ((size_t)(bh*128 + (s>>4))*2 + (d>>5))*512
                        + (size_t)((((d>>3)&3)*16 + (s&15))*8 + (d&7));
                out[idx] = (_Float16)v;
            }
        }
    }
}

// ---------------------------------------------------- pass 1: PV + denominators
// R11 structure; staging now lane-linear (two 4KB halves at tid*16B stride) ->
// conflict-free ds_writes (was 4.19M conflict cycles at tid*32B stride).
__global__ __launch_bounds__(256) void pv_kernel(
    const _Float16* __restrict__ Qf, const _Float16* __restrict__ Kf,
    const _Float16* __restrict__ Vf, const float* __restrict__ emo_bias,
    const float* __restrict__ modv, _Float16* __restrict__ attended,
    float* __restrict__ Ldenom)
{
    __shared__ _Float16 lK[2][4096];      // 2 x 8 KB
    __shared__ _Float16 lV[2][4096];      // 2 x 8 KB

    const int tid  = threadIdx.x;
    const int lane = tid & 63;
    const int l16  = lane & 15;
    const int g    = lane >> 4;
    const int w    = tid >> 6;
    const int n    = blockIdx.x;
    const int work = (n & 7)*128 + (n >> 3);   // bijective for 1024 blocks
    const int qt   = work & 31;
    const int bh   = work >> 5;
    const int b    = bh >> 3, h = bh & 7;
    const int q0   = qt*64 + w*16;

    const float mod = modv[b];
    const float sm2 = 0.125f * mod * LOG2E;
    const float bm2 = emo_bias[h] * mod * LOG2E;

    const size_t fB = (size_t)bh * 128;

    half8_t qf[2];
    #pragma unroll
    for (int c = 0; c < 2; ++c)
        qf[c] = *(const half8_t*)(Qf + ((fB + (q0>>4))*2 + c)*512 + lane*8);

    {   // prologue: lane-linear staging of group 0
        const _Float16* gk = Kf + fB*1024;
        const _Float16* gv = Vf + fB*1024;
        *(half8_t*)(&lK[0][tid*8])        = *(const half8_t*)(gk + tid*8);
        *(half8_t*)(&lK[0][2048 + tid*8]) = *(const half8_t*)(gk + 2048 + tid*8);
        *(half8_t*)(&lV[0][tid*8])        = *(const half8_t*)(gv + tid*8);
        *(half8_t*)(&lV[0][2048 + tid*8]) = *(const half8_t*)(gv + 2048 + tid*8);
    }
    __syncthreads();

    f32x4 acc[4] = {};
    float lsum = 0.f;
    int cur = 0;
    for (int grp = 0; grp < SEQ/64; ++grp){
        half8_t rk0, rk1, rv0, rv1;
        if (grp < SEQ/64 - 1){
            const _Float16* gk = Kf + (fB + (size_t)(grp+1)*4)*1024;
            const _Float16* gv = Vf + (fB + (size_t)(grp+1)*4)*1024;
            rk0 = *(const half8_t*)(gk + tid*8);
            rk1 = *(const half8_t*)(gk + 2048 + tid*8);
            rv0 = *(const half8_t*)(gv + tid*8);
            rv1 = *(const half8_t*)(gv + 2048 + tid*8);
        }
        const _Float16* kb = &lK[cur][0];
        const _Float16* vb = &lV[cur][0];
        #pragma unroll
        for (int t = 0; t < 4; ++t){
            half8_t k0 = *(const half8_t*)(kb + (t*2+0)*512 + lane*8);
            half8_t k1 = *(const half8_t*)(kb + (t*2+1)*512 + lane*8);
            f32x4 s = {};
            s = __builtin_amdgcn_mfma_f32_16x16x32_f16(k0, qf[0], s, 0, 0, 0);
            s = __builtin_amdgcn_mfma_f32_16x16x32_f16(k1, qf[1], s, 0, 0, 0);
            float e0 = EXP2F(s[0]*sm2 + bm2);
            float e1 = EXP2F(s[1]*sm2 + bm2);
            float e2 = EXP2F(s[2]*sm2 + bm2);
            float e3 = EXP2F(s[3]*sm2 + bm2);
            lsum += (e0 + e1) + (e2 + e3);
            half2_t plo = PKRTZ(e0, e1), phi = PKRTZ(e2, e3);
            half4_t pf  = __builtin_shufflevector(plo, phi, 0, 1, 2, 3);
            half8_t vp0 = *(const half8_t*)(vb + (t*2+0)*512 + lane*8);
            half8_t vp1 = *(const half8_t*)(vb + (t*2+1)*512 + lane*8);
            half4_t v0 = __builtin_shufflevector(vp0, vp0, 0, 1, 2, 3);
            half4_t v1 = __builtin_shufflevector(vp0, vp0, 4, 5, 6, 7);
            half4_t v2 = __builtin_shufflevector(vp1, vp1, 0, 1, 2, 3);
            half4_t v3 = __builtin_shufflevector(vp1, vp1, 4, 5, 6, 7);
            acc[0] = __builtin_amdgcn_mfma_f32_16x16x16f16(pf, v0, acc[0], 0, 0, 0);
            acc[1] = __builtin_amdgcn_mfma_f32_16x16x16f16(pf, v1, acc[1], 0, 0, 0);
            acc[2] = __builtin_amdgcn_mfma_f32_16x16x16f16(pf, v2, acc[2], 0, 0, 0);
            acc[3] = __builtin_amdgcn_mfma_f32_16x16x16f16(pf, v3, acc[3], 0, 0, 0);
        }
        if (grp < SEQ/64 - 1){
            *(half8_t*)(&lK[cur^1][tid*8])        = rk0;
            *(half8_t*)(&lK[cur^1][2048 + tid*8]) = rk1;
            *(half8_t*)(&lV[cur^1][tid*8])        = rv0;
            *(half8_t*)(&lV[cur^1][2048 + tid*8]) = rv1;
        }
        __syncthreads();
        cur ^= 1;
    }

    lsum += __shfl_xor(lsum, 16, 64);
    lsum += __shfl_xor(lsum, 32, 64);
    if (g == 0) Ldenom[(size_t)bh*SEQ + q0 + l16] = lsum;
    const float inv = 1.0f / lsum;
    float invr[4];
    #pragma unroll
    for (int r = 0; r < 4; ++r)
        invr[r] = __shfl(inv, 4*g + r, 64);
    #pragma unroll
    for (int c = 0; c < 4; ++c)
        #pragma unroll
        for (int r = 0; r < 4; ++r)
            attended[(size_t)(b*SEQ + q0 + 4*g + r)*EMB + h*64 + 16*c + l16]
                = (_Float16)(acc[c][r] * invr[r]);
}

// ------------------------------------------- pass 2: softmax mean over heads
// (unchanged from R11 — verified)
__global__ __launch_bounds__(256) void mean_kernel(
    const _Float16* __restrict__ Qf, const _Float16* __restrict__ Kf,
    const float* __restrict__ emo_bias, const float* __restrict__ modv,
    const float* __restrict__ Ldenom, float* __restrict__ mean_out)
{
    const int tid  = threadIdx.x;
    const int w    = tid >> 6;
    const int lane = tid & 63;
    const int l16  = lane & 15;
    const int g    = lane >> 4;
    const int n    = blockIdx.x;
    const int work = (n & 7)*512 + (n >> 3);
    const int b    = work >> 10;
    const int ky   = (work >> 7) & 7;
    const int qt   = work & 127;
    const int q0   = qt * 16;
    const int k0w  = ky*256 + w*64;

    const float mod = modv[b];
    const float sm2 = 0.125f * mod * LOG2E;

    f32x4 msum[4] = {};
    for (int hp = 0; hp < HEADS/2; ++hp){
        const int h0 = 2*hp, h1 = 2*hp + 1;
        const size_t lo0 = (size_t)(b*HEADS + h0) * SEQ;
        const size_t lo1 = (size_t)(b*HEADS + h1) * SEQ;
        const size_t f0  = (size_t)(b*HEADS + h0) * 128;
        const size_t f1  = (size_t)(b*HEADS + h1) * 128;
        const float bm20 = emo_bias[h0] * mod * LOG2E;
        const float bm21 = emo_bias[h1] * mod * LOG2E;
        half8_t qa0 = *(const half8_t*)(Qf + ((f0 + (q0>>4))*2 + 0)*512 + lane*8);
        half8_t qa1 = *(const half8_t*)(Qf + ((f0 + (q0>>4))*2 + 1)*512 + lane*8);
        half8_t qb0 = *(const half8_t*)(Qf + ((f1 + (q0>>4))*2 + 0)*512 + lane*8);
        half8_t qb1 = *(const half8_t*)(Qf + ((f1 + (q0>>4))*2 + 1)*512 + lane*8);
        float iA[4], iB[4];
        #pragma unroll
        for (int r = 0; r < 4; ++r){
            iA[r] = 1.0f / Ldenom[lo0 + q0 + 4*g + r];
            iB[r] = 1.0f / Ldenom[lo1 + q0 + 4*g + r];
        }
        #pragma unroll
        for (int j = 0; j < 4; ++j){
            const int kc = (k0w >> 4) + j;
            half8_t ka0 = *(const half8_t*)(Kf + ((f0 + kc)*2 + 0)*512 + lane*8);
            half8_t ka1 = *(const half8_t*)(Kf + ((f0 + kc)*2 + 1)*512 + lane*8);
            half8_t kb0 = *(const half8_t*)(Kf + ((f1 + kc)*2 + 0)*512 + lane*8);
            half8_t kb1 = *(const half8_t*)(Kf + ((f1 + kc)*2 + 1)*512 + lane*8);
            f32x4 sA = {}, sB = {};
            sA = __builtin_amdgcn_mfma_f32_16x16x32_f16(qa0, ka0, sA, 0, 0, 0);
            sA = __builtin_amdgcn_mfma_f32_16x16x32_f16(qa1, ka1, sA, 0, 0, 0);
            sB = __builtin_amdgcn_mfma_f32_16x16x32_f16(qb0, kb0, sB, 0, 0, 0);
            sB = __builtin_amdgcn_mfma_f32_16x16x32_f16(qb1, kb1, sB, 0, 0, 0);
            #pragma unroll
            for (int r = 0; r < 4; ++r){
                float pa = EXP2F(sA[r]*sm2 + bm20) * iA[r];
                float pb = EXP2F(sB[r]*sm2 + bm21) * iB[r];
                msum[j][r] += pa + pb;
            }
        }
    }
    #pragma unroll
    for (int j = 0; j < 4; ++j)
        #pragma unroll
        for (int r = 0; r < 4; ++r)
            mean_out[(size_t)(b*SEQ + q0 + 4*g + r)*SEQ + k0w + j*16 + l16]
                = msum[j][r] * (1.0f/HEADS);
}

// ------------------------------------------------- output projection (LDS GEMM)
// Double-buffered like qkv; A loads are f16 (no cvt), B converts from f32.
__global__ __launch_bounds__(256) void outproj_kernel(
    const _Float16* __restrict__ A, const float* __restrict__ W,
    const float* __restrict__ bias, float* __restrict__ out)
{
    __shared__ _Float16 lA[2][128*64];
    __shared__ _Float16 lB[2][64*64];

    const int tid  = threadIdx.x;
    const int wid  = tid >> 6;
    const int lane = tid & 63;
    const int l16  = lane & 15;
    const int g    = lane >> 4;
    const int l7   = l16 & 7;
    const int mb = blockIdx.x;
    const int nb = blockIdx.y;
    const int wm = (wid >> 1)*64;
    const int wn = (wid & 1)*32;
    const int tR = tid >> 3;
    const int c8 = tid & 7;

    #pragma unroll
    for (int p = 0; p < 4; ++p){
        const int R = p*32 + tR;
        half8_t h = *(const half8_t*)(A + (size_t)(mb*128 + R)*EMB + c8*8);
        *(half8_t*)(&lA[0][R*64 + ((c8 ^ (R & 7))*8)]) = h;
    }
    #pragma unroll
    for (int p = 0; p < 2; ++p){
        const int R = p*32 + tR;
        half8_t h = cvt8(W + (size_t)(nb*64 + R)*EMB + c8*8);
        *(half8_t*)(&lB[0][R*64 + ((c8 ^ (R & 7))*8)]) = h;
    }
    __syncthreads();

    f32x4 acc[4][2] = {};
    int cur = 0;
    for (int ks = 0; ks < 8; ++ks){
        half8_t ra[4];
        float4 wb0[2], wb1[2];
        if (ks < 7){
            #pragma unroll
            for (int p = 0; p < 4; ++p)
                ra[p] = *(const half8_t*)(A + (size_t)(mb*128 + p*32 + tR)*EMB + (ks+1)*64 + c8*8);
            #pragma unroll
            for (int p = 0; p < 2; ++p){
                const float* pw = W + (size_t)(nb*64 + p*32 + tR)*EMB + (ks+1)*64 + c8*8;
                wb0[p] = *(const float4*)pw;
                wb1[p] = *(const float4*)(pw + 4);
            }
        }
        #pragma unroll
        for (int u = 0; u < 2; ++u){
            half8_t af[4], bf[2];
            #pragma unroll
            for (int i = 0; i < 4; ++i){
                const int rA = wm + i*16 + l16;
                af[i] = *(half8_t*)(&lA[cur][rA*64 + (((u*4 + g) ^ l7)*8)]);
            }
            #pragma unroll
            for (int j = 0; j < 2; ++j){
                const int rB = wn + j*16 + l16;
                bf[j] = *(half8_t*)(&lB[cur][rB*64 + (((u*4 + g) ^ l7)*8)]);
            }
            #pragma unroll
            for (int i = 0; i < 4; ++i)
                #pragma unroll
                for (int j = 0; j < 2; ++j)
                    acc[i][j] = __builtin_amdgcn_mfma_f32_16x16x32_f16(af[i], bf[j], acc[i][j], 0, 0, 0);
        }
        if (ks < 7){
            #pragma unroll
            for (int p = 0; p < 4; ++p){
                const int R = p*32 + tR;
                *(half8_t*)(&lA[cur^1][R*64 + ((c8 ^ (R & 7))*8)]) = ra[p];
            }
            #pragma unroll
            for (int p = 0; p < 2; ++p){
                const int R = p*32 + tR;
                *(half8_t*)(&lB[cur^1][R*64 + ((c8 ^ (R & 7))*8)]) = cvt8v(wb0[p], wb1[p]);
            }
        }
        __syncthreads();
        cur ^= 1;
    }
    #pragma unroll
    for (int j = 0; j < 2; ++j){
        const int nn = nb*64 + wn + j*16 + l16;
        const float bn = bias[nn];
        #pragma unroll
        for (int i = 0; i < 4; ++i)
            #pragma unroll
            for (int r = 0; r < 4; ++r){
                const int m = mb*128 + wm + i*16 + 4*g + r;
                out[(size_t)m*EMB + nn] = acc[i][j][r] + bn;
            }
    }
}

// ---------------------------------------------------------------------- host
extern "C" void kernel_launch(void* const* d_in, const int* in_sizes, int n_in,
                              void* d_out, int out_size, void* d_ws, size_t ws_size,
                              hipStream_t stream)
{
    const float* query = (const float*)d_in[0];
    const float* key_  = (const float*)d_in[1];
    const float* value = (const float*)d_in[2];
    const float* emo   = (const float*)d_in[3];
    const float* Wq = (const float*)d_in[4];
    const float* bq = (const float*)d_in[5];
    const float* Wk = (const float*)d_in[6];
    const float* bk = (const float*)d_in[7];
    const float* Wv = (const float*)d_in[8];
    const float* bv = (const float*)d_in[9];
    const float* Wo = (const float*)d_in[10];
    const float* bo = (const float*)d_in[11];
    const float* emo_bias = (const float*)d_in[12];

    const size_t NTOK = (size_t)BATCH * SEQ * EMB;   // 4,194,304
    _Float16* ws       = (_Float16*)d_ws;
    _Float16* Qp       = ws;                          // ws usage: exactly 32 MiB
    _Float16* Kp       = ws + NTOK;
    _Float16* Vt       = ws + 2*NTOK;
    _Float16* attended = ws + 3*NTOK;

    float* out0     = (float*)d_out;
    float* mean_out = out0 + NTOK;
    float* Ldenom   = out0;                           // scratch in out0 region
    float* modv     = out0 + (size_t)BATCH*HEADS*SEQ; // overwritten by outproj

    mod_kernel<<<1, 64, 0, stream>>>(emo, modv);
    qkv_kernel<<<dim3(64, 8, 3), 256, 0, stream>>>(query, key_, value, Wq, Wk, Wv,
                                                   bq, bk, bv, Qp, Kp, Vt);
    pv_kernel<<<BATCH*HEADS*(SEQ/64), 256, 0, stream>>>(Qp, Kp, Vt, emo_bias, modv, attended, Ldenom);
    mean_kernel<<<BATCH*(SEQ/16)*(SEQ/256), 256, 0, stream>>>(Qp, Kp, emo_bias, modv, Ldenom, mean_out);
    outproj_kernel<<<dim3(64, 8), 256, 0, stream>>>(attended, Wo, bo, out0);
}

// Round 13
// 176.267 us; speedup vs baseline: 1.0060x; 1.0060x over previous
//
#include <hip/hip_runtime.h>

#define BATCH 4
#define SEQ   2048
#define EMB   512
#define HEADS 8
#define HD    64

typedef _Float16 half2_t __attribute__((ext_vector_type(2)));
typedef _Float16 half4_t __attribute__((ext_vector_type(4)));
typedef _Float16 half8_t __attribute__((ext_vector_type(8)));
typedef float    f32x4   __attribute__((ext_vector_type(4)));

#if __has_builtin(__builtin_amdgcn_exp2f)
#define EXP2F(x) __builtin_amdgcn_exp2f(x)
#else
#define EXP2F(x) exp2f(x)
#endif
#define LOG2E 1.44269504088896f

#define PKRTZ(a, b) __builtin_bit_cast(half2_t, __builtin_amdgcn_cvt_pkrtz((a), (b)))

// ---------------------------------------------------------------- mod factor
__global__ void mod_kernel(const float* __restrict__ emo, float* __restrict__ modv){
    int lane = threadIdx.x;                 // 64 threads, 1 wave
    for (int b = 0; b < BATCH; ++b){
        float v = emo[b*64 + lane];
        #pragma unroll
        for (int off = 32; off >= 1; off >>= 1) v += __shfl_xor(v, off, 64);
        if (lane == 0){
            float mean = v * (1.0f/64.0f);
            float sig  = 1.0f/(1.0f + __expf(-mean));
            modv[b] = 0.5f + 0.5f*sig;
        }
    }
}

// packed f32->f16 converts (RTZ; staging-only, <=1 ulp f16)
__device__ inline half8_t cvt8pk(float4 v0, float4 v1){
    half2_t p0 = PKRTZ(v0.x, v0.y), p1 = PKRTZ(v0.z, v0.w);
    half2_t p2 = PKRTZ(v1.x, v1.y), p3 = PKRTZ(v1.z, v1.w);
    half4_t a = __builtin_shufflevector(p0, p1, 0, 1, 2, 3);
    half4_t b = __builtin_shufflevector(p2, p3, 0, 1, 2, 3);
    return __builtin_shufflevector(a, b, 0, 1, 2, 3, 4, 5, 6, 7);
}
__device__ inline half8_t cvt8(const float* p){
    return cvt8pk(*(const float4*)p, *(const float4*)(p + 4));
}

// --------------------------------------- QKV projections, one launch (z=0,1,2)
// Single 24KB XOR-swizzled LDS (6 blocks/CU) + EARLY register prefetch: next
// k-step's global loads issue before current compute; write after a barrier.
// Swizzle mapping + fragment-major global outputs identical to R11/R12.
__global__ __launch_bounds__(256) void qkv_kernel(
    const float* __restrict__ X0, const float* __restrict__ X1, const float* __restrict__ X2,
    const float* __restrict__ W0, const float* __restrict__ W1, const float* __restrict__ W2,
    const float* __restrict__ b0, const float* __restrict__ b1, const float* __restrict__ b2,
    _Float16* __restrict__ o0, _Float16* __restrict__ o1, _Float16* __restrict__ o2)
{
    const int z = blockIdx.z;
    const float* X    = (z==0) ? X0 : (z==1) ? X1 : X2;
    const float* W    = (z==0) ? W0 : (z==1) ? W1 : W2;
    const float* bias = (z==0) ? b0 : (z==1) ? b1 : b2;
    _Float16*  out    = (z==0) ? o0 : (z==1) ? o1 : o2;

    __shared__ _Float16 lA[128*64];       // 16 KB row-major, swizzled chunks
    __shared__ _Float16 lB[64*64];        //  8 KB

    const int tid  = threadIdx.x;
    const int wid  = tid >> 6;
    const int lane = tid & 63;
    const int l16  = lane & 15;
    const int g    = lane >> 4;
    const int l7   = l16 & 7;
    const int mb = blockIdx.x;
    const int nb = blockIdx.y;
    const int wm = (wid >> 1)*64;
    const int wn = (wid & 1)*32;
    const int tR = tid >> 3;
    const int c8 = tid & 7;

    // ---- prologue: stage ks=0
    #pragma unroll
    for (int p = 0; p < 4; ++p){
        const int R = p*32 + tR;
        *(half8_t*)(lA + R*64 + ((c8 ^ (R & 7))*8)) = cvt8(X + (size_t)(mb*128 + R)*EMB + c8*8);
    }
    #pragma unroll
    for (int p = 0; p < 2; ++p){
        const int R = p*32 + tR;
        *(half8_t*)(lB + R*64 + ((c8 ^ (R & 7))*8)) = cvt8(W + (size_t)(nb*64 + R)*EMB + c8*8);
    }
    __syncthreads();

    f32x4 acc[4][2] = {};
    for (int ks = 0; ks < 8; ++ks){
        // ---- issue next step's global loads early (hide under compute)
        float4 xa0[4], xa1[4], wb0[2], wb1[2];
        if (ks < 7){
            #pragma unroll
            for (int p = 0; p < 4; ++p){
                const float* px = X + (size_t)(mb*128 + p*32 + tR)*EMB + (ks+1)*64 + c8*8;
                xa0[p] = *(const float4*)px;
                xa1[p] = *(const float4*)(px + 4);
            }
            #pragma unroll
            for (int p = 0; p < 2; ++p){
                const float* pw = W + (size_t)(nb*64 + p*32 + tR)*EMB + (ks+1)*64 + c8*8;
                wb0[p] = *(const float4*)pw;
                wb1[p] = *(const float4*)(pw + 4);
            }
        }
        // ---- compute from LDS
        __builtin_amdgcn_s_setprio(1);
        #pragma unroll
        for (int u = 0; u < 2; ++u){
            half8_t af[4], bf[2];
            #pragma unroll
            for (int i = 0; i < 4; ++i){
                const int rA = wm + i*16 + l16;
                af[i] = *(half8_t*)(lA + rA*64 + (((u*4 + g) ^ l7)*8));
            }
            #pragma unroll
            for (int j = 0; j < 2; ++j){
                const int rB = wn + j*16 + l16;
                bf[j] = *(half8_t*)(lB + rB*64 + (((u*4 + g) ^ l7)*8));
            }
            #pragma unroll
            for (int i = 0; i < 4; ++i)
                #pragma unroll
                for (int j = 0; j < 2; ++j)
                    acc[i][j] = __builtin_amdgcn_mfma_f32_16x16x32_f16(af[i], bf[j], acc[i][j], 0, 0, 0);
        }
        __builtin_amdgcn_s_setprio(0);
        __syncthreads();          // all reads of the buffer done
        if (ks < 7){
            #pragma unroll
            for (int p = 0; p < 4; ++p){
                const int R = p*32 + tR;
                *(half8_t*)(lA + R*64 + ((c8 ^ (R & 7))*8)) = cvt8pk(xa0[p], xa1[p]);
            }
            #pragma unroll
            for (int p = 0; p < 2; ++p){
                const int R = p*32 + tR;
                *(half8_t*)(lB + R*64 + ((c8 ^ (R & 7))*8)) = cvt8pk(wb0[p], wb1[p]);
            }
            __syncthreads();      // buffer refilled
        }
    }
    // ---- store (fragment-major out, mapping identical to R10-R12)
    #pragma unroll
    for (int j = 0; j < 2; ++j){
        const int nn  = nb*64 + wn + j*16 + l16;
        const float bn = bias[nn];
        const int h = nn >> 6, d = nn & 63;
        #pragma unroll
        for (int i = 0; i < 4; ++i){
            #pragma unroll
            for (int r = 0; r < 4; ++r){
                const int m  = mb*128 + wm + i*16 + 4*g + r;
                const int bb2 = m >> 11, s = m & 2047;
                const int bh  = bb2*8 + h;
                const float v = acc[i][j][r] + bn;
                size_t idx;
                if (z == 2)
                    idx = ((size_t)(bh*128 + (s>>4))*2 + (d>>5))*512
                        + (size_t)((((s>>2)&3)*16 + (d&15))*8 + ((d>>4)&1)*4 + (s&3));
                else
                    idx = ((size_t)(bh*128 + (s>>4))*2 + (d>>5))*512
                        + (size_t)((((d>>3)&3)*16 + (s&15))*8 + (d&7));
                out[idx] = (_Float16)v;
            }
        }
    }
}

// ---------------------------------------------------- pass 1: PV + denominators
// R12 structure (lane-linear staging, 0 conflicts) + phase-separated compute
// (all QK -> all exp -> all PV) + setprio around MFMA clusters (T5).
__global__ __launch_bounds__(256) void pv_kernel(
    const _Float16* __restrict__ Qf, const _Float16* __restrict__ Kf,
    const _Float16* __restrict__ Vf, const float* __restrict__ emo_bias,
    const float* __restrict__ modv, _Float16* __restrict__ attended,
    float* __restrict__ Ldenom)
{
    __shared__ _Float16 lK[2][4096];      // 2 x 8 KB
    __shared__ _Float16 lV[2][4096];      // 2 x 8 KB

    const int tid  = threadIdx.x;
    const int lane = tid & 63;
    const int l16  = lane & 15;
    const int g    = lane >> 4;
    const int n    = blockIdx.x;
    const int work = (n & 7)*128 + (n >> 3);   // bijective for 1024 blocks
    const int qt   = work & 31;
    const int bh   = work >> 5;
    const int b    = bh >> 3, h = bh & 7;
    const int q0   = qt*64 + (tid >> 6)*16;

    const float mod = modv[b];
    const float sm2 = 0.125f * mod * LOG2E;
    const float bm2 = emo_bias[h] * mod * LOG2E;

    const size_t fB = (size_t)bh * 128;

    half8_t qf[2];
    #pragma unroll
    for (int c = 0; c < 2; ++c)
        qf[c] = *(const half8_t*)(Qf + ((fB + (q0>>4))*2 + c)*512 + lane*8);

    {   // prologue: lane-linear staging of group 0
        const _Float16* gk = Kf + fB*1024;
        const _Float16* gv = Vf + fB*1024;
        *(half8_t*)(&lK[0][tid*8])        = *(const half8_t*)(gk + tid*8);
        *(half8_t*)(&lK[0][2048 + tid*8]) = *(const half8_t*)(gk + 2048 + tid*8);
        *(half8_t*)(&lV[0][tid*8])        = *(const half8_t*)(gv + tid*8);
        *(half8_t*)(&lV[0][2048 + tid*8]) = *(const half8_t*)(gv + 2048 + tid*8);
    }
    __syncthreads();

    f32x4 acc[4] = {};
    float lsum = 0.f;
    int cur = 0;
    for (int grp = 0; grp < SEQ/64; ++grp){
        half8_t rk0, rk1, rv0, rv1;
        if (grp < SEQ/64 - 1){
            const _Float16* gk = Kf + (fB + (size_t)(grp+1)*4)*1024;
            const _Float16* gv = Vf + (fB + (size_t)(grp+1)*4)*1024;
            rk0 = *(const half8_t*)(gk + tid*8);
            rk1 = *(const half8_t*)(gk + 2048 + tid*8);
            rv0 = *(const half8_t*)(gv + tid*8);
            rv1 = *(const half8_t*)(gv + 2048 + tid*8);
        }
        const _Float16* kb = &lK[cur][0];
        const _Float16* vb = &lV[cur][0];
        // ---- phase 1: all QK (8 MFMAs, 4 independent chains)
        f32x4 s[4];
        __builtin_amdgcn_s_setprio(1);
        #pragma unroll
        for (int t = 0; t < 4; ++t){
            half8_t k0 = *(const half8_t*)(kb + (t*2+0)*512 + lane*8);
            half8_t k1 = *(const half8_t*)(kb + (t*2+1)*512 + lane*8);
            f32x4 zz = {};
            zz = __builtin_amdgcn_mfma_f32_16x16x32_f16(k0, qf[0], zz, 0, 0, 0);
            zz = __builtin_amdgcn_mfma_f32_16x16x32_f16(k1, qf[1], zz, 0, 0, 0);
            s[t] = zz;
        }
        __builtin_amdgcn_s_setprio(0);
        // ---- phase 2: all exp + pack
        half4_t pf[4];
        #pragma unroll
        for (int t = 0; t < 4; ++t){
            float e0 = EXP2F(s[t][0]*sm2 + bm2);
            float e1 = EXP2F(s[t][1]*sm2 + bm2);
            float e2 = EXP2F(s[t][2]*sm2 + bm2);
            float e3 = EXP2F(s[t][3]*sm2 + bm2);
            lsum += (e0 + e1) + (e2 + e3);
            half2_t plo = PKRTZ(e0, e1), phi = PKRTZ(e2, e3);
            pf[t] = __builtin_shufflevector(plo, phi, 0, 1, 2, 3);
        }
        // ---- phase 3: all PV (16 MFMAs, 4 independent acc chains)
        __builtin_amdgcn_s_setprio(1);
        #pragma unroll
        for (int t = 0; t < 4; ++t){
            half8_t vp0 = *(const half8_t*)(vb + (t*2+0)*512 + lane*8);
            half8_t vp1 = *(const half8_t*)(vb + (t*2+1)*512 + lane*8);
            half4_t v0 = __builtin_shufflevector(vp0, vp0, 0, 1, 2, 3);
            half4_t v1 = __builtin_shufflevector(vp0, vp0, 4, 5, 6, 7);
            half4_t v2 = __builtin_shufflevector(vp1, vp1, 0, 1, 2, 3);
            half4_t v3 = __builtin_shufflevector(vp1, vp1, 4, 5, 6, 7);
            acc[0] = __builtin_amdgcn_mfma_f32_16x16x16f16(pf[t], v0, acc[0], 0, 0, 0);
            acc[1] = __builtin_amdgcn_mfma_f32_16x16x16f16(pf[t], v1, acc[1], 0, 0, 0);
            acc[2] = __builtin_amdgcn_mfma_f32_16x16x16f16(pf[t], v2, acc[2], 0, 0, 0);
            acc[3] = __builtin_amdgcn_mfma_f32_16x16x16f16(pf[t], v3, acc[3], 0, 0, 0);
        }
        __builtin_amdgcn_s_setprio(0);
        if (grp < SEQ/64 - 1){
            *(half8_t*)(&lK[cur^1][tid*8])        = rk0;
            *(half8_t*)(&lK[cur^1][2048 + tid*8]) = rk1;
            *(half8_t*)(&lV[cur^1][tid*8])        = rv0;
            *(half8_t*)(&lV[cur^1][2048 + tid*8]) = rv1;
        }
        __syncthreads();
        cur ^= 1;
    }

    lsum += __shfl_xor(lsum, 16, 64);
    lsum += __shfl_xor(lsum, 32, 64);
    if (g == 0) Ldenom[(size_t)bh*SEQ + q0 + l16] = lsum;
    const float inv = 1.0f / lsum;
    float invr[4];
    #pragma unroll
    for (int r = 0; r < 4; ++r)
        invr[r] = __shfl(inv, 4*g + r, 64);
    #pragma unroll
    for (int c = 0; c < 4; ++c)
        #pragma unroll
        for (int r = 0; r < 4; ++r)
            attended[(size_t)(b*SEQ + q0 + 4*g + r)*EMB + h*64 + 16*c + l16]
                = (_Float16)(acc[c][r] * invr[r]);
}

// ------------------------------------------- pass 2: softmax mean over heads
// (unchanged from R12 — verified)
__global__ __launch_bounds__(256) void mean_kernel(
    const _Float16* __restrict__ Qf, const _Float16* __restrict__ Kf,
    const float* __restrict__ emo_bias, const float* __restrict__ modv,
    const float* __restrict__ Ldenom, float* __restrict__ mean_out)
{
    const int tid  = threadIdx.x;
    const int w    = tid >> 6;
    const int lane = tid & 63;
    const int l16  = lane & 15;
    const int g    = lane >> 4;
    const int n    = blockIdx.x;
    const int work = (n & 7)*512 + (n >> 3);
    const int b    = work >> 10;
    const int ky   = (work >> 7) & 7;
    const int qt   = work & 127;
    const int q0   = qt * 16;
    const int k0w  = ky*256 + w*64;

    const float mod = modv[b];
    const float sm2 = 0.125f * mod * LOG2E;

    f32x4 msum[4] = {};
    for (int hp = 0; hp < HEADS/2; ++hp){
        const int h0 = 2*hp, h1 = 2*hp + 1;
        const size_t lo0 = (size_t)(b*HEADS + h0) * SEQ;
        const size_t lo1 = (size_t)(b*HEADS + h1) * SEQ;
        const size_t f0  = (size_t)(b*HEADS + h0) * 128;
        const size_t f1  = (size_t)(b*HEADS + h1) * 128;
        const float bm20 = emo_bias[h0] * mod * LOG2E;
        const float bm21 = emo_bias[h1] * mod * LOG2E;
        half8_t qa0 = *(const half8_t*)(Qf + ((f0 + (q0>>4))*2 + 0)*512 + lane*8);
        half8_t qa1 = *(const half8_t*)(Qf + ((f0 + (q0>>4))*2 + 1)*512 + lane*8);
        half8_t qb0 = *(const half8_t*)(Qf + ((f1 + (q0>>4))*2 + 0)*512 + lane*8);
        half8_t qb1 = *(const half8_t*)(Qf + ((f1 + (q0>>4))*2 + 1)*512 + lane*8);
        float iA[4], iB[4];
        #pragma unroll
        for (int r = 0; r < 4; ++r){
            iA[r] = 1.0f / Ldenom[lo0 + q0 + 4*g + r];
            iB[r] = 1.0f / Ldenom[lo1 + q0 + 4*g + r];
        }
        #pragma unroll
        for (int j = 0; j < 4; ++j){
            const int kc = (k0w >> 4) + j;
            half8_t ka0 = *(const half8_t*)(Kf + ((f0 + kc)*2 + 0)*512 + lane*8);
            half8_t ka1 = *(const half8_t*)(Kf + ((f0 + kc)*2 + 1)*512 + lane*8);
            half8_t kb0 = *(const half8_t*)(Kf + ((f1 + kc)*2 + 0)*512 + lane*8);
            half8_t kb1 = *(const half8_t*)(Kf + ((f1 + kc)*2 + 1)*512 + lane*8);
            f32x4 sA = {}, sB = {};
            sA = __builtin_amdgcn_mfma_f32_16x16x32_f16(qa0, ka0, sA, 0, 0, 0);
            sA = __builtin_amdgcn_mfma_f32_16x16x32_f16(qa1, ka1, sA, 0, 0, 0);
            sB = __builtin_amdgcn_mfma_f32_16x16x32_f16(qb0, kb0, sB, 0, 0, 0);
            sB = __builtin_amdgcn_mfma_f32_16x16x32_f16(qb1, kb1, sB, 0, 0, 0);
            #pragma unroll
            for (int r = 0; r < 4; ++r){
                float pa = EXP2F(sA[r]*sm2 + bm20) * iA[r];
                float pb = EXP2F(sB[r]*sm2 + bm21) * iB[r];
                msum[j][r] += pa + pb;
            }
        }
    }
    #pragma unroll
    for (int j = 0; j < 4; ++j)
        #pragma unroll
        for (int r = 0; r < 4; ++r)
            mean_out[(size_t)(b*SEQ + q0 + 4*g + r)*SEQ + k0w + j*16 + l16]
                = msum[j][r] * (1.0f/HEADS);
}

// ------------------------------------------------- output projection (LDS GEMM)
// Single 24KB buffer + early reg prefetch, like qkv. A is f16 (no cvt).
__global__ __launch_bounds__(256) void outproj_kernel(
    const _Float16* __restrict__ A, const float* __restrict__ W,
    const float* __restrict__ bias, float* __restrict__ out)
{
    __shared__ _Float16 lA[128*64];
    __shared__ _Float16 lB[64*64];

    const int tid  = threadIdx.x;
    const int wid  = tid >> 6;
    const int lane = tid & 63;
    const int l16  = lane & 15;
    const int g    = lane >> 4;
    const int l7   = l16 & 7;
    const int mb = blockIdx.x;
    const int nb = blockIdx.y;
    const int wm = (wid >> 1)*64;
    const int wn = (wid & 1)*32;
    const int tR = tid >> 3;
    const int c8 = tid & 7;

    #pragma unroll
    for (int p = 0; p < 4; ++p){
        const int R = p*32 + tR;
        *(half8_t*)(lA + R*64 + ((c8 ^ (R & 7))*8)) =
            *(const half8_t*)(A + (size_t)(mb*128 + R)*EMB + c8*8);
    }
    #pragma unroll
    for (int p = 0; p < 2; ++p){
        const int R = p*32 + tR;
        *(half8_t*)(lB + R*64 + ((c8 ^ (R & 7))*8)) = cvt8(W + (size_t)(nb*64 + R)*EMB + c8*8);
    }
    __syncthreads();

    f32x4 acc[4][2] = {};
    for (int ks = 0; ks < 8; ++ks){
        half8_t ra[4];
        float4 wb0[2], wb1[2];
        if (ks < 7){
            #pragma unroll
            for (int p = 0; p < 4; ++p)
                ra[p] = *(const half8_t*)(A + (size_t)(mb*128 + p*32 + tR)*EMB + (ks+1)*64 + c8*8);
            #pragma unroll
            for (int p = 0; p < 2; ++p){
                const float* pw = W + (size_t)(nb*64 + p*32 + tR)*EMB + (ks+1)*64 + c8*8;
                wb0[p] = *(const float4*)pw;
                wb1[p] = *(const float4*)(pw + 4);
            }
        }
        __builtin_amdgcn_s_setprio(1);
        #pragma unroll
        for (int u = 0; u < 2; ++u){
            half8_t af[4], bf[2];
            #pragma unroll
            for (int i = 0; i < 4; ++i){
                const int rA = wm + i*16 + l16;
                af[i] = *(half8_t*)(lA + rA*64 + (((u*4 + g) ^ l7)*8));
            }
            #pragma unroll
            for (int j = 0; j < 2; ++j){
                const int rB = wn + j*16 + l16;
                bf[j] = *(half8_t*)(lB + rB*64 + (((u*4 + g) ^ l7)*8));
            }
            #pragma unroll
            for (int i = 0; i < 4; ++i)
                #pragma unroll
                for (int j = 0; j < 2; ++j)
                    acc[i][j] = __builtin_amdgcn_mfma_f32_16x16x32_f16(af[i], bf[j], acc[i][j], 0, 0, 0);
        }
        __builtin_amdgcn_s_setprio(0);
        __syncthreads();
        if (ks < 7){
            #pragma unroll
            for (int p = 0; p < 4; ++p){
                const int R = p*32 + tR;
                *(half8_t*)(lA + R*64 + ((c8 ^ (R & 7))*8)) = ra[p];
            }
            #pragma unroll
            for (int p = 0; p < 2; ++p){
                const int R = p*32 + tR;
                *(half8_t*)(lB + R*64 + ((c8 ^ (R & 7))*8)) = cvt8pk(wb0[p], wb1[p]);
            }
            __syncthreads();
        }
    }
    #pragma unroll
    for (int j = 0; j < 2; ++j){
        const int nn = nb*64 + wn + j*16 + l16;
        const float bn = bias[nn];
        #pragma unroll
        for (int i = 0; i < 4; ++i)
            #pragma unroll
            for (int r = 0; r < 4; ++r){
                const int m = mb*128 + wm + i*16 + 4*g + r;
                out[(size_t)m*EMB + nn] = acc[i][j][r] + bn;
            }
    }
}

// ---------------------------------------------------------------------- host
extern "C" void kernel_launch(void* const* d_in, const int* in_sizes, int n_in,
                              void* d_out, int out_size, void* d_ws, size_t ws_size,
                              hipStream_t stream)
{
    const float* query = (const float*)d_in[0];
    const float* key_  = (const float*)d_in[1];
    const float* value = (const float*)d_in[2];
    const float* emo   = (const float*)d_in[3];
    const float* Wq = (const float*)d_in[4];
    const float* bq = (const float*)d_in[5];
    const float* Wk = (const float*)d_in[6];
    const float* bk = (const float*)d_in[7];
    const float* Wv = (const float*)d_in[8];
    const float* bv = (const float*)d_in[9];
    const float* Wo = (const float*)d_in[10];
    const float* bo = (const float*)d_in[11];
    const float* emo_bias = (const float*)d_in[12];

    const size_t NTOK = (size_t)BATCH * SEQ * EMB;   // 4,194,304
    _Float16* ws       = (_Float16*)d_ws;
    _Float16* Qp       = ws;                          // ws usage: exactly 32 MiB
    _Float16* Kp       = ws + NTOK;
    _Float16* Vt       = ws + 2*NTOK;
    _Float16* attended = ws + 3*NTOK;

    float* out0     = (float*)d_out;
    float* mean_out = out0 + NTOK;
    float* Ldenom   = out0;                           // scratch in out0 region
    float* modv     = out0 + (size_t)BATCH*HEADS*SEQ; // overwritten by outproj

    mod_kernel<<<1, 64, 0, stream>>>(emo, modv);
    qkv_kernel<<<dim3(64, 8, 3), 256, 0, stream>>>(query, key_, value, Wq, Wk, Wv,
                                                   bq, bk, bv, Qp, Kp, Vt);
    pv_kernel<<<BATCH*HEADS*(SEQ/64), 256, 0, stream>>>(Qp, Kp, Vt, emo_bias, modv, attended, Ldenom);
    mean_kernel<<<BATCH*(SEQ/16)*(SEQ/256), 256, 0, stream>>>(Qp, Kp, emo_bias, modv, Ldenom, mean_out);
    outproj_kernel<<<dim3(64, 8), 256, 0, stream>>>(attended, Wo, bo, out0);
}

// Round 14
// 163.291 us; speedup vs baseline: 1.0860x; 1.0795x over previous
//
#include <hip/hip_runtime.h>

#define BATCH 4
#define SEQ   2048
#define EMB   512
#define HEADS 8
#define HD    64

typedef _Float16 half2_t __attribute__((ext_vector_type(2)));
typedef _Float16 half4_t __attribute__((ext_vector_type(4)));
typedef _Float16 half8_t __attribute__((ext_vector_type(8)));
typedef float    f32x4   __attribute__((ext_vector_type(4)));

#if __has_builtin(__builtin_amdgcn_exp2f)
#define EXP2F(x) __builtin_amdgcn_exp2f(x)
#else
#define EXP2F(x) exp2f(x)
#endif
#define LOG2E 1.44269504088896f

#define PKRTZ(a, b) __builtin_bit_cast(half2_t, __builtin_amdgcn_cvt_pkrtz((a), (b)))

// ---------------------------------------------------------------- mod factor
__global__ void mod_kernel(const float* __restrict__ emo, float* __restrict__ modv){
    int lane = threadIdx.x;                 // 64 threads, 1 wave
    for (int b = 0; b < BATCH; ++b){
        float v = emo[b*64 + lane];
        #pragma unroll
        for (int off = 32; off >= 1; off >>= 1) v += __shfl_xor(v, off, 64);
        if (lane == 0){
            float mean = v * (1.0f/64.0f);
            float sig  = 1.0f/(1.0f + __expf(-mean));
            modv[b] = 0.5f + 0.5f*sig;
        }
    }
}

// packed f32->f16 converts (RTZ; staging-only, <=1 ulp f16)
__device__ inline half8_t cvt8pk(float4 v0, float4 v1){
    half2_t p0 = PKRTZ(v0.x, v0.y), p1 = PKRTZ(v0.z, v0.w);
    half2_t p2 = PKRTZ(v1.x, v1.y), p3 = PKRTZ(v1.z, v1.w);
    half4_t a = __builtin_shufflevector(p0, p1, 0, 1, 2, 3);
    half4_t b = __builtin_shufflevector(p2, p3, 0, 1, 2, 3);
    return __builtin_shufflevector(a, b, 0, 1, 2, 3, 4, 5, 6, 7);
}
__device__ inline half8_t cvt8(const float* p){
    return cvt8pk(*(const float4*)p, *(const float4*)(p + 4));
}

// --------------------------------------- QKV projections, one launch (z=0,1,2)
// (unchanged from R13 — verified)
__global__ __launch_bounds__(256) void qkv_kernel(
    const float* __restrict__ X0, const float* __restrict__ X1, const float* __restrict__ X2,
    const float* __restrict__ W0, const float* __restrict__ W1, const float* __restrict__ W2,
    const float* __restrict__ b0, const float* __restrict__ b1, const float* __restrict__ b2,
    _Float16* __restrict__ o0, _Float16* __restrict__ o1, _Float16* __restrict__ o2)
{
    const int z = blockIdx.z;
    const float* X    = (z==0) ? X0 : (z==1) ? X1 : X2;
    const float* W    = (z==0) ? W0 : (z==1) ? W1 : W2;
    const float* bias = (z==0) ? b0 : (z==1) ? b1 : b2;
    _Float16*  out    = (z==0) ? o0 : (z==1) ? o1 : o2;

    __shared__ _Float16 lA[128*64];       // 16 KB row-major, swizzled chunks
    __shared__ _Float16 lB[64*64];        //  8 KB

    const int tid  = threadIdx.x;
    const int wid  = tid >> 6;
    const int lane = tid & 63;
    const int l16  = lane & 15;
    const int g    = lane >> 4;
    const int l7   = l16 & 7;
    const int mb = blockIdx.x;
    const int nb = blockIdx.y;
    const int wm = (wid >> 1)*64;
    const int wn = (wid & 1)*32;
    const int tR = tid >> 3;
    const int c8 = tid & 7;

    #pragma unroll
    for (int p = 0; p < 4; ++p){
        const int R = p*32 + tR;
        *(half8_t*)(lA + R*64 + ((c8 ^ (R & 7))*8)) = cvt8(X + (size_t)(mb*128 + R)*EMB + c8*8);
    }
    #pragma unroll
    for (int p = 0; p < 2; ++p){
        const int R = p*32 + tR;
        *(half8_t*)(lB + R*64 + ((c8 ^ (R & 7))*8)) = cvt8(W + (size_t)(nb*64 + R)*EMB + c8*8);
    }
    __syncthreads();

    f32x4 acc[4][2] = {};
    for (int ks = 0; ks < 8; ++ks){
        float4 xa0[4], xa1[4], wb0[2], wb1[2];
        if (ks < 7){
            #pragma unroll
            for (int p = 0; p < 4; ++p){
                const float* px = X + (size_t)(mb*128 + p*32 + tR)*EMB + (ks+1)*64 + c8*8;
                xa0[p] = *(const float4*)px;
                xa1[p] = *(const float4*)(px + 4);
            }
            #pragma unroll
            for (int p = 0; p < 2; ++p){
                const float* pw = W + (size_t)(nb*64 + p*32 + tR)*EMB + (ks+1)*64 + c8*8;
                wb0[p] = *(const float4*)pw;
                wb1[p] = *(const float4*)(pw + 4);
            }
        }
        __builtin_amdgcn_s_setprio(1);
        #pragma unroll
        for (int u = 0; u < 2; ++u){
            half8_t af[4], bf[2];
            #pragma unroll
            for (int i = 0; i < 4; ++i){
                const int rA = wm + i*16 + l16;
                af[i] = *(half8_t*)(lA + rA*64 + (((u*4 + g) ^ l7)*8));
            }
            #pragma unroll
            for (int j = 0; j < 2; ++j){
                const int rB = wn + j*16 + l16;
                bf[j] = *(half8_t*)(lB + rB*64 + (((u*4 + g) ^ l7)*8));
            }
            #pragma unroll
            for (int i = 0; i < 4; ++i)
                #pragma unroll
                for (int j = 0; j < 2; ++j)
                    acc[i][j] = __builtin_amdgcn_mfma_f32_16x16x32_f16(af[i], bf[j], acc[i][j], 0, 0, 0);
        }
        __builtin_amdgcn_s_setprio(0);
        __syncthreads();
        if (ks < 7){
            #pragma unroll
            for (int p = 0; p < 4; ++p){
                const int R = p*32 + tR;
                *(half8_t*)(lA + R*64 + ((c8 ^ (R & 7))*8)) = cvt8pk(xa0[p], xa1[p]);
            }
            #pragma unroll
            for (int p = 0; p < 2; ++p){
                const int R = p*32 + tR;
                *(half8_t*)(lB + R*64 + ((c8 ^ (R & 7))*8)) = cvt8pk(wb0[p], wb1[p]);
            }
            __syncthreads();
        }
    }
    #pragma unroll
    for (int j = 0; j < 2; ++j){
        const int nn  = nb*64 + wn + j*16 + l16;
        const float bn = bias[nn];
        const int h = nn >> 6, d = nn & 63;
        #pragma unroll
        for (int i = 0; i < 4; ++i){
            #pragma unroll
            for (int r = 0; r < 4; ++r){
                const int m  = mb*128 + wm + i*16 + 4*g + r;
                const int bb2 = m >> 11, s = m & 2047;
                const int bh  = bb2*8 + h;
                const float v = acc[i][j][r] + bn;
                size_t idx;
                if (z == 2)
                    idx = ((size_t)(bh*128 + (s>>4))*2 + (d>>5))*512
                        + (size_t)((((s>>2)&3)*16 + (d&15))*8 + ((d>>4)&1)*4 + (s&3));
                else
                    idx = ((size_t)(bh*128 + (s>>4))*2 + (d>>5))*512
                        + (size_t)((((d>>3)&3)*16 + (s&15))*8 + (d&7));
                out[idx] = (_Float16)v;
            }
        }
    }
}

// ---------------------------------------------------- pass 1: PV + denominators
// (unchanged from R13 — verified)
__global__ __launch_bounds__(256) void pv_kernel(
    const _Float16* __restrict__ Qf, const _Float16* __restrict__ Kf,
    const _Float16* __restrict__ Vf, const float* __restrict__ emo_bias,
    const float* __restrict__ modv, _Float16* __restrict__ attended,
    float* __restrict__ Ldenom)
{
    __shared__ _Float16 lK[2][4096];      // 2 x 8 KB
    __shared__ _Float16 lV[2][4096];      // 2 x 8 KB

    const int tid  = threadIdx.x;
    const int lane = tid & 63;
    const int l16  = lane & 15;
    const int g    = lane >> 4;
    const int n    = blockIdx.x;
    const int work = (n & 7)*128 + (n >> 3);   // bijective for 1024 blocks
    const int qt   = work & 31;
    const int bh   = work >> 5;
    const int b    = bh >> 3, h = bh & 7;
    const int q0   = qt*64 + (tid >> 6)*16;

    const float mod = modv[b];
    const float sm2 = 0.125f * mod * LOG2E;
    const float bm2 = emo_bias[h] * mod * LOG2E;

    const size_t fB = (size_t)bh * 128;

    half8_t qf[2];
    #pragma unroll
    for (int c = 0; c < 2; ++c)
        qf[c] = *(const half8_t*)(Qf + ((fB + (q0>>4))*2 + c)*512 + lane*8);

    {   // prologue: lane-linear staging of group 0
        const _Float16* gk = Kf + fB*1024;
        const _Float16* gv = Vf + fB*1024;
        *(half8_t*)(&lK[0][tid*8])        = *(const half8_t*)(gk + tid*8);
        *(half8_t*)(&lK[0][2048 + tid*8]) = *(const half8_t*)(gk + 2048 + tid*8);
        *(half8_t*)(&lV[0][tid*8])        = *(const half8_t*)(gv + tid*8);
        *(half8_t*)(&lV[0][2048 + tid*8]) = *(const half8_t*)(gv + 2048 + tid*8);
    }
    __syncthreads();

    f32x4 acc[4] = {};
    float lsum = 0.f;
    int cur = 0;
    for (int grp = 0; grp < SEQ/64; ++grp){
        half8_t rk0, rk1, rv0, rv1;
        if (grp < SEQ/64 - 1){
            const _Float16* gk = Kf + (fB + (size_t)(grp+1)*4)*1024;
            const _Float16* gv = Vf + (fB + (size_t)(grp+1)*4)*1024;
            rk0 = *(const half8_t*)(gk + tid*8);
            rk1 = *(const half8_t*)(gk + 2048 + tid*8);
            rv0 = *(const half8_t*)(gv + tid*8);
            rv1 = *(const half8_t*)(gv + 2048 + tid*8);
        }
        const _Float16* kb = &lK[cur][0];
        const _Float16* vb = &lV[cur][0];
        f32x4 s[4];
        __builtin_amdgcn_s_setprio(1);
        #pragma unroll
        for (int t = 0; t < 4; ++t){
            half8_t k0 = *(const half8_t*)(kb + (t*2+0)*512 + lane*8);
            half8_t k1 = *(const half8_t*)(kb + (t*2+1)*512 + lane*8);
            f32x4 zz = {};
            zz = __builtin_amdgcn_mfma_f32_16x16x32_f16(k0, qf[0], zz, 0, 0, 0);
            zz = __builtin_amdgcn_mfma_f32_16x16x32_f16(k1, qf[1], zz, 0, 0, 0);
            s[t] = zz;
        }
        __builtin_amdgcn_s_setprio(0);
        half4_t pf[4];
        #pragma unroll
        for (int t = 0; t < 4; ++t){
            float e0 = EXP2F(s[t][0]*sm2 + bm2);
            float e1 = EXP2F(s[t][1]*sm2 + bm2);
            float e2 = EXP2F(s[t][2]*sm2 + bm2);
            float e3 = EXP2F(s[t][3]*sm2 + bm2);
            lsum += (e0 + e1) + (e2 + e3);
            half2_t plo = PKRTZ(e0, e1), phi = PKRTZ(e2, e3);
            pf[t] = __builtin_shufflevector(plo, phi, 0, 1, 2, 3);
        }
        __builtin_amdgcn_s_setprio(1);
        #pragma unroll
        for (int t = 0; t < 4; ++t){
            half8_t vp0 = *(const half8_t*)(vb + (t*2+0)*512 + lane*8);
            half8_t vp1 = *(const half8_t*)(vb + (t*2+1)*512 + lane*8);
            half4_t v0 = __builtin_shufflevector(vp0, vp0, 0, 1, 2, 3);
            half4_t v1 = __builtin_shufflevector(vp0, vp0, 4, 5, 6, 7);
            half4_t v2 = __builtin_shufflevector(vp1, vp1, 0, 1, 2, 3);
            half4_t v3 = __builtin_shufflevector(vp1, vp1, 4, 5, 6, 7);
            acc[0] = __builtin_amdgcn_mfma_f32_16x16x16f16(pf[t], v0, acc[0], 0, 0, 0);
            acc[1] = __builtin_amdgcn_mfma_f32_16x16x16f16(pf[t], v1, acc[1], 0, 0, 0);
            acc[2] = __builtin_amdgcn_mfma_f32_16x16x16f16(pf[t], v2, acc[2], 0, 0, 0);
            acc[3] = __builtin_amdgcn_mfma_f32_16x16x16f16(pf[t], v3, acc[3], 0, 0, 0);
        }
        __builtin_amdgcn_s_setprio(0);
        if (grp < SEQ/64 - 1){
            *(half8_t*)(&lK[cur^1][tid*8])        = rk0;
            *(half8_t*)(&lK[cur^1][2048 + tid*8]) = rk1;
            *(half8_t*)(&lV[cur^1][tid*8])        = rv0;
            *(half8_t*)(&lV[cur^1][2048 + tid*8]) = rv1;
        }
        __syncthreads();
        cur ^= 1;
    }

    lsum += __shfl_xor(lsum, 16, 64);
    lsum += __shfl_xor(lsum, 32, 64);
    if (g == 0) Ldenom[(size_t)bh*SEQ + q0 + l16] = lsum;
    const float inv = 1.0f / lsum;
    float invr[4];
    #pragma unroll
    for (int r = 0; r < 4; ++r)
        invr[r] = __shfl(inv, 4*g + r, 64);
    #pragma unroll
    for (int c = 0; c < 4; ++c)
        #pragma unroll
        for (int r = 0; r < 4; ++r)
            attended[(size_t)(b*SEQ + q0 + 4*g + r)*EMB + h*64 + 16*c + l16]
                = (_Float16)(acc[c][r] * invr[r]);
}

// ------------------------------------------- pass 2: softmax mean over heads
// 32 q-rows (2 tiles) per block, grid 2048: K-fragment loads shared by both
// tiles (VMEM per output halved). Normalization FOLDED into the exponent:
// p = 2^(s*sm2 + bm2 - log2(L)) — deletes the per-element mul (~25% VALU).
__global__ __launch_bounds__(256) void mean_kernel(
    const _Float16* __restrict__ Qf, const _Float16* __restrict__ Kf,
    const float* __restrict__ emo_bias, const float* __restrict__ modv,
    const float* __restrict__ Ldenom, float* __restrict__ mean_out)
{
    const int tid  = threadIdx.x;
    const int w    = tid >> 6;
    const int lane = tid & 63;
    const int l16  = lane & 15;
    const int g    = lane >> 4;
    // 2048 blocks, bijective XCD swizzle
    const int n    = blockIdx.x;
    const int work = (n & 7)*256 + (n >> 3);
    const int b    = work >> 9;            // 512 work items per batch
    const int ky   = (work >> 6) & 7;      // 8 k-ranges of 256
    const int qt   = work & 63;            // 64 32-row q-tiles
    const int q0   = qt * 32;
    const int k0w  = ky*256 + w*64;

    const float mod = modv[b];
    const float sm2 = 0.125f * mod * LOG2E;

    f32x4 msum[2][4] = {};                 // [tile][j]; lane: q=q0+T*16+4g+r, k=k0w+j*16+l16
    for (int hp = 0; hp < HEADS/2; ++hp){
        const int h0 = 2*hp, h1 = 2*hp + 1;
        const size_t lo0 = (size_t)(b*HEADS + h0) * SEQ;
        const size_t lo1 = (size_t)(b*HEADS + h1) * SEQ;
        const size_t f0  = (size_t)(b*HEADS + h0) * 128;
        const size_t f1  = (size_t)(b*HEADS + h1) * 128;
        const float bm20 = emo_bias[h0] * mod * LOG2E;
        const float bm21 = emo_bias[h1] * mod * LOG2E;
        half8_t qA[2][2], qB[2][2];        // [tile][chunk]
        float elA[2][4], elB[2][4];        // folded exponent offsets
        #pragma unroll
        for (int T = 0; T < 2; ++T){
            const int qr = q0 + T*16;
            #pragma unroll
            for (int c = 0; c < 2; ++c){
                qA[T][c] = *(const half8_t*)(Qf + ((f0 + (qr>>4))*2 + c)*512 + lane*8);
                qB[T][c] = *(const half8_t*)(Qf + ((f1 + (qr>>4))*2 + c)*512 + lane*8);
            }
            #pragma unroll
            for (int r = 0; r < 4; ++r){
                elA[T][r] = bm20 - __log2f(Ldenom[lo0 + qr + 4*g + r]);
                elB[T][r] = bm21 - __log2f(Ldenom[lo1 + qr + 4*g + r]);
            }
        }
        #pragma unroll
        for (int j = 0; j < 4; ++j){
            const int kc = (k0w >> 4) + j;
            half8_t ka0 = *(const half8_t*)(Kf + ((f0 + kc)*2 + 0)*512 + lane*8);
            half8_t ka1 = *(const half8_t*)(Kf + ((f0 + kc)*2 + 1)*512 + lane*8);
            half8_t kb0 = *(const half8_t*)(Kf + ((f1 + kc)*2 + 0)*512 + lane*8);
            half8_t kb1 = *(const half8_t*)(Kf + ((f1 + kc)*2 + 1)*512 + lane*8);
            #pragma unroll
            for (int T = 0; T < 2; ++T){
                f32x4 sA = {}, sB = {};
                sA = __builtin_amdgcn_mfma_f32_16x16x32_f16(qA[T][0], ka0, sA, 0, 0, 0);
                sA = __builtin_amdgcn_mfma_f32_16x16x32_f16(qA[T][1], ka1, sA, 0, 0, 0);
                sB = __builtin_amdgcn_mfma_f32_16x16x32_f16(qB[T][0], kb0, sB, 0, 0, 0);
                sB = __builtin_amdgcn_mfma_f32_16x16x32_f16(qB[T][1], kb1, sB, 0, 0, 0);
                #pragma unroll
                for (int r = 0; r < 4; ++r)
                    msum[T][j][r] += EXP2F(sA[r]*sm2 + elA[T][r])
                                   + EXP2F(sB[r]*sm2 + elB[T][r]);
            }
        }
    }
    #pragma unroll
    for (int T = 0; T < 2; ++T)
        #pragma unroll
        for (int j = 0; j < 4; ++j)
            #pragma unroll
            for (int r = 0; r < 4; ++r)
                mean_out[(size_t)(b*SEQ + q0 + T*16 + 4*g + r)*SEQ + k0w + j*16 + l16]
                    = msum[T][j][r] * (1.0f/HEADS);
}

// ------------------------------------------------- output projection (LDS GEMM)
// (unchanged from R13 — verified)
__global__ __launch_bounds__(256) void outproj_kernel(
    const _Float16* __restrict__ A, const float* __restrict__ W,
    const float* __restrict__ bias, float* __restrict__ out)
{
    __shared__ _Float16 lA[128*64];
    __shared__ _Float16 lB[64*64];

    const int tid  = threadIdx.x;
    const int wid  = tid >> 6;
    const int lane = tid & 63;
    const int l16  = lane & 15;
    const int g    = lane >> 4;
    const int l7   = l16 & 7;
    const int mb = blockIdx.x;
    const int nb = blockIdx.y;
    const int wm = (wid >> 1)*64;
    const int wn = (wid & 1)*32;
    const int tR = tid >> 3;
    const int c8 = tid & 7;

    #pragma unroll
    for (int p = 0; p < 4; ++p){
        const int R = p*32 + tR;
        *(half8_t*)(lA + R*64 + ((c8 ^ (R & 7))*8)) =
            *(const half8_t*)(A + (size_t)(mb*128 + R)*EMB + c8*8);
    }
    #pragma unroll
    for (int p = 0; p < 2; ++p){
        const int R = p*32 + tR;
        *(half8_t*)(lB + R*64 + ((c8 ^ (R & 7))*8)) = cvt8(W + (size_t)(nb*64 + R)*EMB + c8*8);
    }
    __syncthreads();

    f32x4 acc[4][2] = {};
    for (int ks = 0; ks < 8; ++ks){
        half8_t ra[4];
        float4 wb0[2], wb1[2];
        if (ks < 7){
            #pragma unroll
            for (int p = 0; p < 4; ++p)
                ra[p] = *(const half8_t*)(A + (size_t)(mb*128 + p*32 + tR)*EMB + (ks+1)*64 + c8*8);
            #pragma unroll
            for (int p = 0; p < 2; ++p){
                const float* pw = W + (size_t)(nb*64 + p*32 + tR)*EMB + (ks+1)*64 + c8*8;
                wb0[p] = *(const float4*)pw;
                wb1[p] = *(const float4*)(pw + 4);
            }
        }
        __builtin_amdgcn_s_setprio(1);
        #pragma unroll
        for (int u = 0; u < 2; ++u){
            half8_t af[4], bf[2];
            #pragma unroll
            for (int i = 0; i < 4; ++i){
                const int rA = wm + i*16 + l16;
                af[i] = *(half8_t*)(lA + rA*64 + (((u*4 + g) ^ l7)*8));
            }
            #pragma unroll
            for (int j = 0; j < 2; ++j){
                const int rB = wn + j*16 + l16;
                bf[j] = *(half8_t*)(lB + rB*64 + (((u*4 + g) ^ l7)*8));
            }
            #pragma unroll
            for (int i = 0; i < 4; ++i)
                #pragma unroll
                for (int j = 0; j < 2; ++j)
                    acc[i][j] = __builtin_amdgcn_mfma_f32_16x16x32_f16(af[i], bf[j], acc[i][j], 0, 0, 0);
        }
        __builtin_amdgcn_s_setprio(0);
        __syncthreads();
        if (ks < 7){
            #pragma unroll
            for (int p = 0; p < 4; ++p){
                const int R = p*32 + tR;
                *(half8_t*)(lA + R*64 + ((c8 ^ (R & 7))*8)) = ra[p];
            }
            #pragma unroll
            for (int p = 0; p < 2; ++p){
                const int R = p*32 + tR;
                *(half8_t*)(lB + R*64 + ((c8 ^ (R & 7))*8)) = cvt8pk(wb0[p], wb1[p]);
            }
            __syncthreads();
        }
    }
    #pragma unroll
    for (int j = 0; j < 2; ++j){
        const int nn = nb*64 + wn + j*16 + l16;
        const float bn = bias[nn];
        #pragma unroll
        for (int i = 0; i < 4; ++i)
            #pragma unroll
            for (int r = 0; r < 4; ++r){
                const int m = mb*128 + wm + i*16 + 4*g + r;
                out[(size_t)m*EMB + nn] = acc[i][j][r] + bn;
            }
    }
}

// ---------------------------------------------------------------------- host
extern "C" void kernel_launch(void* const* d_in, const int* in_sizes, int n_in,
                              void* d_out, int out_size, void* d_ws, size_t ws_size,
                              hipStream_t stream)
{
    const float* query = (const float*)d_in[0];
    const float* key_  = (const float*)d_in[1];
    const float* value = (const float*)d_in[2];
    const float* emo   = (const float*)d_in[3];
    const float* Wq = (const float*)d_in[4];
    const float* bq = (const float*)d_in[5];
    const float* Wk = (const float*)d_in[6];
    const float* bk = (const float*)d_in[7];
    const float* Wv = (const float*)d_in[8];
    const float* bv = (const float*)d_in[9];
    const float* Wo = (const float*)d_in[10];
    const float* bo = (const float*)d_in[11];
    const float* emo_bias = (const float*)d_in[12];

    const size_t NTOK = (size_t)BATCH * SEQ * EMB;   // 4,194,304
    _Float16* ws       = (_Float16*)d_ws;
    _Float16* Qp       = ws;                          // ws usage: exactly 32 MiB
    _Float16* Kp       = ws + NTOK;
    _Float16* Vt       = ws + 2*NTOK;
    _Float16* attended = ws + 3*NTOK;

    float* out0     = (float*)d_out;
    float* mean_out = out0 + NTOK;
    float* Ldenom   = out0;                           // scratch in out0 region
    float* modv     = out0 + (size_t)BATCH*HEADS*SEQ; // overwritten by outproj

    mod_kernel<<<1, 64, 0, stream>>>(emo, modv);
    qkv_kernel<<<dim3(64, 8, 3), 256, 0, stream>>>(query, key_, value, Wq, Wk, Wv,
                                                   bq, bk, bv, Qp, Kp, Vt);
    pv_kernel<<<BATCH*HEADS*(SEQ/64), 256, 0, stream>>>(Qp, Kp, Vt, emo_bias, modv, attended, Ldenom);
    mean_kernel<<<BATCH*(SEQ/32)*(SEQ/256), 256, 0, stream>>>(Qp, Kp, emo_bias, modv, Ldenom, mean_out);
    outproj_kernel<<<dim3(64, 8), 256, 0, stream>>>(attended, Wo, bo, out0);
}

// Round 15
// 162.264 us; speedup vs baseline: 1.0928x; 1.0063x over previous
//
#include <hip/hip_runtime.h>

#define BATCH 4
#define SEQ   2048
#define EMB   512
#define HEADS 8
#define HD    64

typedef _Float16 half2_t __attribute__((ext_vector_type(2)));
typedef _Float16 half4_t __attribute__((ext_vector_type(4)));
typedef _Float16 half8_t __attribute__((ext_vector_type(8)));
typedef float    f32x4   __attribute__((ext_vector_type(4)));

#if __has_builtin(__builtin_amdgcn_exp2f)
#define EXP2F(x) __builtin_amdgcn_exp2f(x)
#else
#define EXP2F(x) exp2f(x)
#endif
#define LOG2E 1.44269504088896f

#define PKRTZ(a, b) __builtin_bit_cast(half2_t, __builtin_amdgcn_cvt_pkrtz((a), (b)))

// ---------------------------------------------------------------- mod factor
__global__ void mod_kernel(const float* __restrict__ emo, float* __restrict__ modv){
    int lane = threadIdx.x;                 // 64 threads, 1 wave
    for (int b = 0; b < BATCH; ++b){
        float v = emo[b*64 + lane];
        #pragma unroll
        for (int off = 32; off >= 1; off >>= 1) v += __shfl_xor(v, off, 64);
        if (lane == 0){
            float mean = v * (1.0f/64.0f);
            float sig  = 1.0f/(1.0f + __expf(-mean));
            modv[b] = 0.5f + 0.5f*sig;
        }
    }
}

// packed f32->f16 converts (RTZ; staging-only, <=1 ulp f16)
__device__ inline half8_t cvt8pk(float4 v0, float4 v1){
    half2_t p0 = PKRTZ(v0.x, v0.y), p1 = PKRTZ(v0.z, v0.w);
    half2_t p2 = PKRTZ(v1.x, v1.y), p3 = PKRTZ(v1.z, v1.w);
    half4_t a = __builtin_shufflevector(p0, p1, 0, 1, 2, 3);
    half4_t b = __builtin_shufflevector(p2, p3, 0, 1, 2, 3);
    return __builtin_shufflevector(a, b, 0, 1, 2, 3, 4, 5, 6, 7);
}
__device__ inline half8_t cvt8(const float* p){
    return cvt8pk(*(const float4*)p, *(const float4*)(p + 4));
}

// --------------------------------------- QKV projections, one launch (z=0,1,2)
// (unchanged from R14 — verified)
__global__ __launch_bounds__(256) void qkv_kernel(
    const float* __restrict__ X0, const float* __restrict__ X1, const float* __restrict__ X2,
    const float* __restrict__ W0, const float* __restrict__ W1, const float* __restrict__ W2,
    const float* __restrict__ b0, const float* __restrict__ b1, const float* __restrict__ b2,
    _Float16* __restrict__ o0, _Float16* __restrict__ o1, _Float16* __restrict__ o2)
{
    const int z = blockIdx.z;
    const float* X    = (z==0) ? X0 : (z==1) ? X1 : X2;
    const float* W    = (z==0) ? W0 : (z==1) ? W1 : W2;
    const float* bias = (z==0) ? b0 : (z==1) ? b1 : b2;
    _Float16*  out    = (z==0) ? o0 : (z==1) ? o1 : o2;

    __shared__ _Float16 lA[128*64];       // 16 KB row-major, swizzled chunks
    __shared__ _Float16 lB[64*64];        //  8 KB

    const int tid  = threadIdx.x;
    const int wid  = tid >> 6;
    const int lane = tid & 63;
    const int l16  = lane & 15;
    const int g    = lane >> 4;
    const int l7   = l16 & 7;
    const int mb = blockIdx.x;
    const int nb = blockIdx.y;
    const int wm = (wid >> 1)*64;
    const int wn = (wid & 1)*32;
    const int tR = tid >> 3;
    const int c8 = tid & 7;

    #pragma unroll
    for (int p = 0; p < 4; ++p){
        const int R = p*32 + tR;
        *(half8_t*)(lA + R*64 + ((c8 ^ (R & 7))*8)) = cvt8(X + (size_t)(mb*128 + R)*EMB + c8*8);
    }
    #pragma unroll
    for (int p = 0; p < 2; ++p){
        const int R = p*32 + tR;
        *(half8_t*)(lB + R*64 + ((c8 ^ (R & 7))*8)) = cvt8(W + (size_t)(nb*64 + R)*EMB + c8*8);
    }
    __syncthreads();

    f32x4 acc[4][2] = {};
    for (int ks = 0; ks < 8; ++ks){
        float4 xa0[4], xa1[4], wb0[2], wb1[2];
        if (ks < 7){
            #pragma unroll
            for (int p = 0; p < 4; ++p){
                const float* px = X + (size_t)(mb*128 + p*32 + tR)*EMB + (ks+1)*64 + c8*8;
                xa0[p] = *(const float4*)px;
                xa1[p] = *(const float4*)(px + 4);
            }
            #pragma unroll
            for (int p = 0; p < 2; ++p){
                const float* pw = W + (size_t)(nb*64 + p*32 + tR)*EMB + (ks+1)*64 + c8*8;
                wb0[p] = *(const float4*)pw;
                wb1[p] = *(const float4*)(pw + 4);
            }
        }
        __builtin_amdgcn_s_setprio(1);
        #pragma unroll
        for (int u = 0; u < 2; ++u){
            half8_t af[4], bf[2];
            #pragma unroll
            for (int i = 0; i < 4; ++i){
                const int rA = wm + i*16 + l16;
                af[i] = *(half8_t*)(lA + rA*64 + (((u*4 + g) ^ l7)*8));
            }
            #pragma unroll
            for (int j = 0; j < 2; ++j){
                const int rB = wn + j*16 + l16;
                bf[j] = *(half8_t*)(lB + rB*64 + (((u*4 + g) ^ l7)*8));
            }
            #pragma unroll
            for (int i = 0; i < 4; ++i)
                #pragma unroll
                for (int j = 0; j < 2; ++j)
                    acc[i][j] = __builtin_amdgcn_mfma_f32_16x16x32_f16(af[i], bf[j], acc[i][j], 0, 0, 0);
        }
        __builtin_amdgcn_s_setprio(0);
        __syncthreads();
        if (ks < 7){
            #pragma unroll
            for (int p = 0; p < 4; ++p){
                const int R = p*32 + tR;
                *(half8_t*)(lA + R*64 + ((c8 ^ (R & 7))*8)) = cvt8pk(xa0[p], xa1[p]);
            }
            #pragma unroll
            for (int p = 0; p < 2; ++p){
                const int R = p*32 + tR;
                *(half8_t*)(lB + R*64 + ((c8 ^ (R & 7))*8)) = cvt8pk(wb0[p], wb1[p]);
            }
            __syncthreads();
        }
    }
    #pragma unroll
    for (int j = 0; j < 2; ++j){
        const int nn  = nb*64 + wn + j*16 + l16;
        const float bn = bias[nn];
        const int h = nn >> 6, d = nn & 63;
        #pragma unroll
        for (int i = 0; i < 4; ++i){
            #pragma unroll
            for (int r = 0; r < 4; ++r){
                const int m  = mb*128 + wm + i*16 + 4*g + r;
                const int bb2 = m >> 11, s = m & 2047;
                const int bh  = bb2*8 + h;
                const float v = acc[i][j][r] + bn;
                size_t idx;
                if (z == 2)
                    idx = ((size_t)(bh*128 + (s>>4))*2 + (d>>5))*512
                        + (size_t)((((s>>2)&3)*16 + (d&15))*8 + ((d>>4)&1)*4 + (s&3));
                else
                    idx = ((size_t)(bh*128 + (s>>4))*2 + (d>>5))*512
                        + (size_t)((((d>>3)&3)*16 + (s&15))*8 + (d&7));
                out[idx] = (_Float16)v;
            }
        }
    }
}

// ---------------------------------------------------- pass 1: PV + denominators
// R14 structure + rowsum-by-MFMA: a 5th accumulator acc5 = mfma(pf, ones, acc5)
// computes L(q) on the matrix pipe (B==1 -> D[q][*] = sum_k p[q][k]), deleting
// the 16 lsum VALU adds per group and the shfl reduction tail. acc5[r] holds
// L for q = q0+4g+r (C/D row = 4g+r), matching the attended/Ldenom indexing.
__global__ __launch_bounds__(256) void pv_kernel(
    const _Float16* __restrict__ Qf, const _Float16* __restrict__ Kf,
    const _Float16* __restrict__ Vf, const float* __restrict__ emo_bias,
    const float* __restrict__ modv, _Float16* __restrict__ attended,
    float* __restrict__ Ldenom)
{
    __shared__ _Float16 lK[2][4096];      // 2 x 8 KB
    __shared__ _Float16 lV[2][4096];      // 2 x 8 KB

    const int tid  = threadIdx.x;
    const int lane = tid & 63;
    const int l16  = lane & 15;
    const int g    = lane >> 4;
    const int n    = blockIdx.x;
    const int work = (n & 7)*128 + (n >> 3);   // bijective for 1024 blocks
    const int qt   = work & 31;
    const int bh   = work >> 5;
    const int b    = bh >> 3, h = bh & 7;
    const int q0   = qt*64 + (tid >> 6)*16;

    const float mod = modv[b];
    const float sm2 = 0.125f * mod * LOG2E;
    const float bm2 = emo_bias[h] * mod * LOG2E;

    const size_t fB = (size_t)bh * 128;

    half8_t qf[2];
    #pragma unroll
    for (int c = 0; c < 2; ++c)
        qf[c] = *(const half8_t*)(Qf + ((fB + (q0>>4))*2 + c)*512 + lane*8);

    {   // prologue: lane-linear staging of group 0
        const _Float16* gk = Kf + fB*1024;
        const _Float16* gv = Vf + fB*1024;
        *(half8_t*)(&lK[0][tid*8])        = *(const half8_t*)(gk + tid*8);
        *(half8_t*)(&lK[0][2048 + tid*8]) = *(const half8_t*)(gk + 2048 + tid*8);
        *(half8_t*)(&lV[0][tid*8])        = *(const half8_t*)(gv + tid*8);
        *(half8_t*)(&lV[0][2048 + tid*8]) = *(const half8_t*)(gv + 2048 + tid*8);
    }
    __syncthreads();

    const half4_t ones4 = {(_Float16)1.0f, (_Float16)1.0f, (_Float16)1.0f, (_Float16)1.0f};
    f32x4 acc[4] = {};
    f32x4 acc5 = {};                      // rowsums (softmax denominators)
    int cur = 0;
    for (int grp = 0; grp < SEQ/64; ++grp){
        half8_t rk0, rk1, rv0, rv1;
        if (grp < SEQ/64 - 1){
            const _Float16* gk = Kf + (fB + (size_t)(grp+1)*4)*1024;
            const _Float16* gv = Vf + (fB + (size_t)(grp+1)*4)*1024;
            rk0 = *(const half8_t*)(gk + tid*8);
            rk1 = *(const half8_t*)(gk + 2048 + tid*8);
            rv0 = *(const half8_t*)(gv + tid*8);
            rv1 = *(const half8_t*)(gv + 2048 + tid*8);
        }
        const _Float16* kb = &lK[cur][0];
        const _Float16* vb = &lV[cur][0];
        f32x4 s[4];
        __builtin_amdgcn_s_setprio(1);
        #pragma unroll
        for (int t = 0; t < 4; ++t){
            half8_t k0 = *(const half8_t*)(kb + (t*2+0)*512 + lane*8);
            half8_t k1 = *(const half8_t*)(kb + (t*2+1)*512 + lane*8);
            f32x4 zz = {};
            zz = __builtin_amdgcn_mfma_f32_16x16x32_f16(k0, qf[0], zz, 0, 0, 0);
            zz = __builtin_amdgcn_mfma_f32_16x16x32_f16(k1, qf[1], zz, 0, 0, 0);
            s[t] = zz;
        }
        __builtin_amdgcn_s_setprio(0);
        half4_t pf[4];
        #pragma unroll
        for (int t = 0; t < 4; ++t){
            float e0 = EXP2F(s[t][0]*sm2 + bm2);
            float e1 = EXP2F(s[t][1]*sm2 + bm2);
            float e2 = EXP2F(s[t][2]*sm2 + bm2);
            float e3 = EXP2F(s[t][3]*sm2 + bm2);
            half2_t plo = PKRTZ(e0, e1), phi = PKRTZ(e2, e3);
            pf[t] = __builtin_shufflevector(plo, phi, 0, 1, 2, 3);
        }
        __builtin_amdgcn_s_setprio(1);
        #pragma unroll
        for (int t = 0; t < 4; ++t){
            half8_t vp0 = *(const half8_t*)(vb + (t*2+0)*512 + lane*8);
            half8_t vp1 = *(const half8_t*)(vb + (t*2+1)*512 + lane*8);
            half4_t v0 = __builtin_shufflevector(vp0, vp0, 0, 1, 2, 3);
            half4_t v1 = __builtin_shufflevector(vp0, vp0, 4, 5, 6, 7);
            half4_t v2 = __builtin_shufflevector(vp1, vp1, 0, 1, 2, 3);
            half4_t v3 = __builtin_shufflevector(vp1, vp1, 4, 5, 6, 7);
            acc5   = __builtin_amdgcn_mfma_f32_16x16x16f16(pf[t], ones4, acc5, 0, 0, 0);
            acc[0] = __builtin_amdgcn_mfma_f32_16x16x16f16(pf[t], v0, acc[0], 0, 0, 0);
            acc[1] = __builtin_amdgcn_mfma_f32_16x16x16f16(pf[t], v1, acc[1], 0, 0, 0);
            acc[2] = __builtin_amdgcn_mfma_f32_16x16x16f16(pf[t], v2, acc[2], 0, 0, 0);
            acc[3] = __builtin_amdgcn_mfma_f32_16x16x16f16(pf[t], v3, acc[3], 0, 0, 0);
        }
        __builtin_amdgcn_s_setprio(0);
        if (grp < SEQ/64 - 1){
            *(half8_t*)(&lK[cur^1][tid*8])        = rk0;
            *(half8_t*)(&lK[cur^1][2048 + tid*8]) = rk1;
            *(half8_t*)(&lV[cur^1][tid*8])        = rv0;
            *(half8_t*)(&lV[cur^1][2048 + tid*8]) = rv1;
        }
        __syncthreads();
        cur ^= 1;
    }

    // acc5[r] = L(q0+4g+r), identical across l16. Store Ldenom (l16==0 lanes
    // cover all 16 q) and normalize attended directly.
    if (l16 == 0){
        #pragma unroll
        for (int r = 0; r < 4; ++r)
            Ldenom[(size_t)bh*SEQ + q0 + 4*g + r] = acc5[r];
    }
    float invr[4];
    #pragma unroll
    for (int r = 0; r < 4; ++r)
        invr[r] = 1.0f / acc5[r];
    #pragma unroll
    for (int c = 0; c < 4; ++c)
        #pragma unroll
        for (int r = 0; r < 4; ++r)
            attended[(size_t)(b*SEQ + q0 + 4*g + r)*EMB + h*64 + 16*c + l16]
                = (_Float16)(acc[c][r] * invr[r]);
}

// ------------------------------------------- pass 2: softmax mean over heads
// (unchanged from R14 — verified)
__global__ __launch_bounds__(256) void mean_kernel(
    const _Float16* __restrict__ Qf, const _Float16* __restrict__ Kf,
    const float* __restrict__ emo_bias, const float* __restrict__ modv,
    const float* __restrict__ Ldenom, float* __restrict__ mean_out)
{
    const int tid  = threadIdx.x;
    const int w    = tid >> 6;
    const int lane = tid & 63;
    const int l16  = lane & 15;
    const int g    = lane >> 4;
    // 2048 blocks, bijective XCD swizzle
    const int n    = blockIdx.x;
    const int work = (n & 7)*256 + (n >> 3);
    const int b    = work >> 9;            // 512 work items per batch
    const int ky   = (work >> 6) & 7;      // 8 k-ranges of 256
    const int qt   = work & 63;            // 64 32-row q-tiles
    const int q0   = qt * 32;
    const int k0w  = ky*256 + w*64;

    const float mod = modv[b];
    const float sm2 = 0.125f * mod * LOG2E;

    f32x4 msum[2][4] = {};                 // [tile][j]; lane: q=q0+T*16+4g+r, k=k0w+j*16+l16
    for (int hp = 0; hp < HEADS/2; ++hp){
        const int h0 = 2*hp, h1 = 2*hp + 1;
        const size_t lo0 = (size_t)(b*HEADS + h0) * SEQ;
        const size_t lo1 = (size_t)(b*HEADS + h1) * SEQ;
        const size_t f0  = (size_t)(b*HEADS + h0) * 128;
        const size_t f1  = (size_t)(b*HEADS + h1) * 128;
        const float bm20 = emo_bias[h0] * mod * LOG2E;
        const float bm21 = emo_bias[h1] * mod * LOG2E;
        half8_t qA[2][2], qB[2][2];        // [tile][chunk]
        float elA[2][4], elB[2][4];        // folded exponent offsets
        #pragma unroll
        for (int T = 0; T < 2; ++T){
            const int qr = q0 + T*16;
            #pragma unroll
            for (int c = 0; c < 2; ++c){
                qA[T][c] = *(const half8_t*)(Qf + ((f0 + (qr>>4))*2 + c)*512 + lane*8);
                qB[T][c] = *(const half8_t*)(Qf + ((f1 + (qr>>4))*2 + c)*512 + lane*8);
            }
            #pragma unroll
            for (int r = 0; r < 4; ++r){
                elA[T][r] = bm20 - __log2f(Ldenom[lo0 + qr + 4*g + r]);
                elB[T][r] = bm21 - __log2f(Ldenom[lo1 + qr + 4*g + r]);
            }
        }
        #pragma unroll
        for (int j = 0; j < 4; ++j){
            const int kc = (k0w >> 4) + j;
            half8_t ka0 = *(const half8_t*)(Kf + ((f0 + kc)*2 + 0)*512 + lane*8);
            half8_t ka1 = *(const half8_t*)(Kf + ((f0 + kc)*2 + 1)*512 + lane*8);
            half8_t kb0 = *(const half8_t*)(Kf + ((f1 + kc)*2 + 0)*512 + lane*8);
            half8_t kb1 = *(const half8_t*)(Kf + ((f1 + kc)*2 + 1)*512 + lane*8);
            #pragma unroll
            for (int T = 0; T < 2; ++T){
                f32x4 sA = {}, sB = {};
                sA = __builtin_amdgcn_mfma_f32_16x16x32_f16(qA[T][0], ka0, sA, 0, 0, 0);
                sA = __builtin_amdgcn_mfma_f32_16x16x32_f16(qA[T][1], ka1, sA, 0, 0, 0);
                sB = __builtin_amdgcn_mfma_f32_16x16x32_f16(qB[T][0], kb0, sB, 0, 0, 0);
                sB = __builtin_amdgcn_mfma_f32_16x16x32_f16(qB[T][1], kb1, sB, 0, 0, 0);
                #pragma unroll
                for (int r = 0; r < 4; ++r)
                    msum[T][j][r] += EXP2F(sA[r]*sm2 + elA[T][r])
                                   + EXP2F(sB[r]*sm2 + elB[T][r]);
            }
        }
    }
    #pragma unroll
    for (int T = 0; T < 2; ++T)
        #pragma unroll
        for (int j = 0; j < 4; ++j)
            #pragma unroll
            for (int r = 0; r < 4; ++r)
                mean_out[(size_t)(b*SEQ + q0 + T*16 + 4*g + r)*SEQ + k0w + j*16 + l16]
                    = msum[T][j][r] * (1.0f/HEADS);
}

// ------------------------------------------------- output projection (LDS GEMM)
// (unchanged from R14 — verified)
__global__ __launch_bounds__(256) void outproj_kernel(
    const _Float16* __restrict__ A, const float* __restrict__ W,
    const float* __restrict__ bias, float* __restrict__ out)
{
    __shared__ _Float16 lA[128*64];
    __shared__ _Float16 lB[64*64];

    const int tid  = threadIdx.x;
    const int wid  = tid >> 6;
    const int lane = tid & 63;
    const int l16  = lane & 15;
    const int g    = lane >> 4;
    const int l7   = l16 & 7;
    const int mb = blockIdx.x;
    const int nb = blockIdx.y;
    const int wm = (wid >> 1)*64;
    const int wn = (wid & 1)*32;
    const int tR = tid >> 3;
    const int c8 = tid & 7;

    #pragma unroll
    for (int p = 0; p < 4; ++p){
        const int R = p*32 + tR;
        *(half8_t*)(lA + R*64 + ((c8 ^ (R & 7))*8)) =
            *(const half8_t*)(A + (size_t)(mb*128 + R)*EMB + c8*8);
    }
    #pragma unroll
    for (int p = 0; p < 2; ++p){
        const int R = p*32 + tR;
        *(half8_t*)(lB + R*64 + ((c8 ^ (R & 7))*8)) = cvt8(W + (size_t)(nb*64 + R)*EMB + c8*8);
    }
    __syncthreads();

    f32x4 acc[4][2] = {};
    for (int ks = 0; ks < 8; ++ks){
        half8_t ra[4];
        float4 wb0[2], wb1[2];
        if (ks < 7){
            #pragma unroll
            for (int p = 0; p < 4; ++p)
                ra[p] = *(const half8_t*)(A + (size_t)(mb*128 + p*32 + tR)*EMB + (ks+1)*64 + c8*8);
            #pragma unroll
            for (int p = 0; p < 2; ++p){
                const float* pw = W + (size_t)(nb*64 + p*32 + tR)*EMB + (ks+1)*64 + c8*8;
                wb0[p] = *(const float4*)pw;
                wb1[p] = *(const float4*)(pw + 4);
            }
        }
        __builtin_amdgcn_s_setprio(1);
        #pragma unroll
        for (int u = 0; u < 2; ++u){
            half8_t af[4], bf[2];
            #pragma unroll
            for (int i = 0; i < 4; ++i){
                const int rA = wm + i*16 + l16;
                af[i] = *(half8_t*)(lA + rA*64 + (((u*4 + g) ^ l7)*8));
            }
            #pragma unroll
            for (int j = 0; j < 2; ++j){
                const int rB = wn + j*16 + l16;
                bf[j] = *(half8_t*)(lB + rB*64 + (((u*4 + g) ^ l7)*8));
            }
            #pragma unroll
            for (int i = 0; i < 4; ++i)
                #pragma unroll
                for (int j = 0; j < 2; ++j)
                    acc[i][j] = __builtin_amdgcn_mfma_f32_16x16x32_f16(af[i], bf[j], acc[i][j], 0, 0, 0);
        }
        __builtin_amdgcn_s_setprio(0);
        __syncthreads();
        if (ks < 7){
            #pragma unroll
            for (int p = 0; p < 4; ++p){
                const int R = p*32 + tR;
                *(half8_t*)(lA + R*64 + ((c8 ^ (R & 7))*8)) = ra[p];
            }
            #pragma unroll
            for (int p = 0; p < 2; ++p){
                const int R = p*32 + tR;
                *(half8_t*)(lB + R*64 + ((c8 ^ (R & 7))*8)) = cvt8pk(wb0[p], wb1[p]);
            }
            __syncthreads();
        }
    }
    #pragma unroll
    for (int j = 0; j < 2; ++j){
        const int nn = nb*64 + wn + j*16 + l16;
        const float bn = bias[nn];
        #pragma unroll
        for (int i = 0; i < 4; ++i)
            #pragma unroll
            for (int r = 0; r < 4; ++r){
                const int m = mb*128 + wm + i*16 + 4*g + r;
                out[(size_t)m*EMB + nn] = acc[i][j][r] + bn;
            }
    }
}

// ---------------------------------------------------------------------- host
extern "C" void kernel_launch(void* const* d_in, const int* in_sizes, int n_in,
                              void* d_out, int out_size, void* d_ws, size_t ws_size,
                              hipStream_t stream)
{
    const float* query = (const float*)d_in[0];
    const float* key_  = (const float*)d_in[1];
    const float* value = (const float*)d_in[2];
    const float* emo   = (const float*)d_in[3];
    const float* Wq = (const float*)d_in[4];
    const float* bq = (const float*)d_in[5];
    const float* Wk = (const float*)d_in[6];
    const float* bk = (const float*)d_in[7];
    const float* Wv = (const float*)d_in[8];
    const float* bv = (const float*)d_in[9];
    const float* Wo = (const float*)d_in[10];
    const float* bo = (const float*)d_in[11];
    const float* emo_bias = (const float*)d_in[12];

    const size_t NTOK = (size_t)BATCH * SEQ * EMB;   // 4,194,304
    _Float16* ws       = (_Float16*)d_ws;
    _Float16* Qp       = ws;                          // ws usage: exactly 32 MiB
    _Float16* Kp       = ws + NTOK;
    _Float16* Vt       = ws + 2*NTOK;
    _Float16* attended = ws + 3*NTOK;

    float* out0     = (float*)d_out;
    float* mean_out = out0 + NTOK;
    float* Ldenom   = out0;                           // scratch in out0 region
    float* modv     = out0 + (size_t)BATCH*HEADS*SEQ; // overwritten by outproj

    mod_kernel<<<1, 64, 0, stream>>>(emo, modv);
    qkv_kernel<<<dim3(64, 8, 3), 256, 0, stream>>>(query, key_, value, Wq, Wk, Wv,
                                                   bq, bk, bv, Qp, Kp, Vt);
    pv_kernel<<<BATCH*HEADS*(SEQ/64), 256, 0, stream>>>(Qp, Kp, Vt, emo_bias, modv, attended, Ldenom);
    mean_kernel<<<BATCH*(SEQ/32)*(SEQ/256), 256, 0, stream>>>(Qp, Kp, emo_bias, modv, Ldenom, mean_out);
    outproj_kernel<<<dim3(64, 8), 256, 0, stream>>>(attended, Wo, bo, out0);
}